// Round 25
// baseline (150.933 us; speedup 1.0000x reference)
//
#include <hip/hip_runtime.h>

#define F_ 8
#define C_ 128
#define C2_ (C_/2)   // 64 c-pairs
#define H_ 96
#define W_ 96
#define P_ (H_*W_)   // 9216
#define I_ 64
#define I2_ (I_/2)   // 32 i-pairs
#define T_ 17
#define KK_ (F_*T_)  // 136

// compile-time tap offsets (full unroll -> immediates) — used by k_scores / yr path
__device__ constexpr int DY[T_] = {-1,-1,-1, 0,0,0, 1,1,1, -3,-3,-3, 0,0, 3,3,3};
__device__ constexpr int DX[T_] = {-1, 0, 1,-1,0,1,-1,0,1, -3, 0, 3,-3,3,-3,0,3};

// dy-grouped tap order for k_y path (consecutive taps share cache lines)
__constant__ int CDY[T_] = {-3,-3,-3, -1,-1,-1,  0, 0,0,0, 0,  1,1,1,  3, 3, 3};
__constant__ int CDX[T_] = {-3, 0, 3, -1, 0, 1, -3,-1,0,1, 3, -1,0,1, -3, 0, 3};
__constant__ int CK [T_] = { 9,10,11,  0, 1, 2, 12, 3,4,5,13,  6,7,8, 14,15,16};

typedef unsigned short u16;
typedef u16 u16x8 __attribute__((ext_vector_type(8)));
typedef short s16x8 __attribute__((ext_vector_type(8)));
typedef float f32x2 __attribute__((ext_vector_type(2)));
typedef float f32x4 __attribute__((ext_vector_type(4)));
typedef _Float16 h16x2 __attribute__((ext_vector_type(2)));
typedef _Float16 h16x8 __attribute__((ext_vector_type(8)));

__device__ __forceinline__ float b2f(u16 u) { return __uint_as_float(((unsigned)u) << 16); }
__device__ __forceinline__ u16 f2b(float f) {
    unsigned u = __float_as_uint(f);
    u += 0x7fff + ((u >> 16) & 1);   // RNE
    return (u16)(u >> 16);
}
__device__ __forceinline__ h16x2 u2h(unsigned u) {
    union { unsigned u; h16x2 h; } x; x.u = u; return x.h;
}
__device__ __forceinline__ unsigned packh(float a, float b) {
    union { unsigned u; h16x2 h; } x;
    x.h[0] = (_Float16)a; x.h[1] = (_Float16)b; return x.u;
}
__device__ __forceinline__ h16x2 slice2(h16x8 v, int j) {
    h16x2 r; r[0] = v[2*j]; r[1] = v[2*j+1]; return r;
}
__device__ __forceinline__ float dot2(h16x2 a, h16x2 b, float c) {
#if __has_builtin(__builtin_amdgcn_fdot2)
    return __builtin_amdgcn_fdot2(a, b, c, false);
#else
    return c + (float)a[0] * (float)b[0] + (float)a[1] * (float)b[1];
#endif
}

// vt[c], u[c] fp32; uh = fp16-pair-packed u; ct[0]=wt.rtb; ct[1]=wp.rpb
__global__ __launch_bounds__(128) void k_prep(const float* __restrict__ rtw,
                                              const float* __restrict__ rpw,
                                              const float* __restrict__ rtb,
                                              const float* __restrict__ rpb,
                                              const float* __restrict__ cp,
                                              float* __restrict__ vt,
                                              float* __restrict__ u,
                                              float* __restrict__ ct,
                                              unsigned* __restrict__ uh) {
    __shared__ float su[C_];
    int c = threadIdx.x;  // 128
    float a = 0.f, b2 = 0.f;
    for (int i = 0; i < I_; ++i) {
        a  += cp[i]      * rtw[i*C_ + c];
        b2 += cp[I_ + i] * rpw[i*C_ + c];
    }
    vt[c] = a; u[c] = b2; su[c] = b2;
    if (c == 0) { float s = 0.f; for (int i = 0; i < I_; ++i) s += cp[i]      * rtb[i]; ct[0] = s; }
    if (c == 1) { float s = 0.f; for (int i = 0; i < I_; ++i) s += cp[I_ + i] * rpb[i]; ct[1] = s; }
    __syncthreads();
    if (c < C2_) uh[c] = packh(su[2*c], su[2*c+1]);
}

// merged weight prep: blocks [0,104): Wpk+ball; [104,168): Wpk2+ball2; [168,200): rgT
__global__ __launch_bounds__(256) void k_wprep(const float* __restrict__ g_w,
                                               const float* __restrict__ th_w,
                                               const float* __restrict__ ph_w,
                                               const float* __restrict__ g_b,
                                               const float* __restrict__ th_b,
                                               const float* __restrict__ ph_b,
                                               const float* __restrict__ u,
                                               const float* __restrict__ ct,
                                               const float* __restrict__ W_w,
                                               const float* __restrict__ rW_w,
                                               const float* __restrict__ Wb,
                                               const float* __restrict__ rWb,
                                               const float* __restrict__ rg_w,
                                               _Float16* __restrict__ Wpk,
                                               float* __restrict__ ball,
                                               u16* __restrict__ Wpk2,
                                               float* __restrict__ ball2,
                                               float* __restrict__ rgT) {
    int b = blockIdx.x;
    if (b < 104) {
        int idx = b * 256 + threadIdx.x;   // over 13*4*64*8 = 26624
        if (idx < 26624) {
            int j    = idx & 7;
            int frag = idx >> 3;
            int l    = frag & 63;
            int t    = frag >> 6;      // nt*4 + ks
            int ks   = t & 3;
            int nt   = t >> 2;
            int c = ks * 32 + ((l >> 4) << 3) + j;
            int n = nt * 16 + (l & 15);
            float v;
            if (n < 192) {
                int proj = n >> 6, i = n & 63;
                const float* src = proj == 0 ? g_w : (proj == 1 ? th_w : ph_w);
                v = src[i * C_ + c];
            } else if (n == 192) v = u[c];
            else v = 0.f;
            Wpk[idx] = (_Float16)v;
        }
        if (idx < 208) {
            float bb;
            if (idx < 192) {
                int proj = idx >> 6, i = idx & 63;
                const float* bs = proj == 0 ? g_b : (proj == 1 ? th_b : ph_b);
                bb = bs[i];
            } else if (idx == 192) bb = ct[1];
            else bb = 0.f;
            ball[idx] = bb;
        }
    } else if (b < 168) {
        int idx = (b - 104) * 256 + threadIdx.x;   // over 16384
        if (idx < 16384) {
            int j    = idx & 7;
            int frag = idx >> 3;
            int l    = frag & 63;
            int t    = frag >> 6;
            int ks   = t & 3;
            int nt   = t >> 2;
            int k = ks * 32 + ((l >> 4) << 3) + j;   // i' 0..127
            int n = nt * 16 + (l & 15);              // c 0..127
            float v = (k < 64) ? W_w[n * I_ + k] : rW_w[n * I_ + (k - 64)];
            Wpk2[idx] = f2b(v);
        }
        if (idx < C_) ball2[idx] = Wb[idx] + rWb[idx];
    } else {
        int idx = (b - 168) * 256 + threadIdx.x;   // over 8192
        int r = idx / C_, c = idx % C_;
        rgT[c*I_ + r] = rg_w[idx];
    }
}

// MERGED: y<32 -> x->fp16 xhT[f][p][c]; y>=32 -> rg conv (GR) / SR field
__global__ __launch_bounds__(256) void k_xr(const float* __restrict__ x,
                                            const float* __restrict__ rgb,
                                            const float* __restrict__ rgT,
                                            const float* __restrict__ rg_b,
                                            const float* __restrict__ vt,
                                            const float* __restrict__ ct,
                                            _Float16* __restrict__ xhT,
                                            float* __restrict__ GR,
                                            float* __restrict__ SR) {
    int yb = blockIdx.y;
    int p  = blockIdx.x * 256 + threadIdx.x;
    if (yb < 32) {
        int cb = yb & 3;          // 4 blocks of 32 c
        int f  = yb >> 2;
        const float* xp = x + ((size_t)f * C_ + cb * 32) * P_ + p;
        unsigned r[16];
#pragma unroll
        for (int jj = 0; jj < 16; ++jj) {
            float a = xp[(size_t)(2 * jj)     * P_];
            float b = xp[(size_t)(2 * jj + 1) * P_];
            r[jj] = packh(a, b);
        }
        unsigned* dst = (unsigned*)(xhT + ((size_t)f * P_ + p) * C_ + cb * 32);
#pragma unroll
        for (int q4 = 0; q4 < 4; ++q4) {
            uint4 v; v.x = r[q4*4]; v.y = r[q4*4+1]; v.z = r[q4*4+2]; v.w = r[q4*4+3];
            *(uint4*)(dst + q4 * 4) = v;
        }
        return;
    }
    int y = yb - 32;              // 0..4
    if (y == 4) {
        float s = ct[0];
        for (int c = 0; c < C_; ++c) s += rgb[(size_t)c * P_ + p] * vt[c];
        SR[p] = s;
        return;
    }
    int i0 = y * 16;
    float acc[16];
#pragma unroll
    for (int ii = 0; ii < 16; ++ii) acc[ii] = 0.f;
#pragma unroll 2
    for (int c = 0; c < C_; ++c) {
        float xv = rgb[(size_t)c * P_ + p];
        const float* wr = rgT + (size_t)c * I_ + i0;
#pragma unroll
        for (int ii = 0; ii < 16; ++ii) acc[ii] += xv * wr[ii];
    }
#pragma unroll
    for (int ii = 0; ii < 16; ++ii) GR[(size_t)(i0 + ii) * P_ + p] = acc[ii] + rg_b[i0 + ii];
}

// MFMA projections: per f, D[n=0..207][px] = W^T x. 16x16x32 f16, fp32 accum.
// Outputs interleaved [f][ib][p][8] fp16 (each lane: 4 consecutive i -> one uint2).
__global__ __launch_bounds__(256) void k_projm(const _Float16* __restrict__ xhT,
                                               const h16x8* __restrict__ Wpk,
                                               const float* __restrict__ ball,
                                               u16* __restrict__ oG,
                                               u16* __restrict__ oT,
                                               u16* __restrict__ oP,
                                               float* __restrict__ Bf) {
    int wid  = threadIdx.x >> 6;
    int lane = threadIdx.x & 63;
    int px0  = blockIdx.x * 64 + wid * 16;
    int f    = blockIdx.z;
    int lm   = lane & 15;
    int lg   = lane >> 4;
    const _Float16* xrow = xhT + ((size_t)f * P_ + px0 + lm) * C_ + lg * 8;
    h16x8 bfrag[4];
#pragma unroll
    for (int ks = 0; ks < 4; ++ks)
        bfrag[ks] = *(const h16x8*)(xrow + ks * 32);
#pragma unroll 1
    for (int nt = 0; nt < 13; ++nt) {
        f32x4 acc = {0.f, 0.f, 0.f, 0.f};
#pragma unroll
        for (int ks = 0; ks < 4; ++ks) {
            h16x8 afrag = Wpk[(nt * 4 + ks) * 64 + lane];
            acc = __builtin_amdgcn_mfma_f32_16x16x32_f16(afrag, bfrag[ks], acc, 0, 0, 0);
        }
        int nb = nt * 16 + lg * 4;     // 4 consecutive n in regs 0..3
        if (nb < 192) {
            int proj = nb >> 6, i = nb & 63;
            int ib = i >> 3, i7 = i & 7;   // i7 in {0,4} -> 8B aligned uint2
            u16* o = proj == 0 ? oG : (proj == 1 ? oT : oP);
            size_t base = (((size_t)f * 8 + ib) * P_ + px0 + lm) * 8 + i7;
            uint2 v;
            v.x = packh(acc[0] + ball[nb],     acc[1] + ball[nb + 1]);
            v.y = packh(acc[2] + ball[nb + 2], acc[3] + ball[nb + 3]);
            *(uint2*)(o + base) = v;
        } else if (nb == 192) {
            Bf[(size_t)f * P_ + px0 + lm] = acc[0] + ball[192];
        }
    }
}

// scores: S[k][p][f1] (bf16) = exp(mask * sum_i PH.TH)
// interleaved PH/TH: per ib, 8 coalesced PH h16x8 + 4 gathered TH h16x8 -> 32 dot2x4
__global__ __launch_bounds__(256) void k_scores(const u16* __restrict__ PH,
                                                const u16* __restrict__ TH,
                                                u16* __restrict__ S) {
    int p  = blockIdx.x * 256 + threadIdx.x;
    int k0 = blockIdx.y * 4;
    int px = p % W_, py = p / W_;
    int qs[4], f2s[4]; float msk[4];
#pragma unroll
    for (int kk = 0; kk < 4; ++kk) {
        int k  = k0 + kk;
        int f2 = k / T_;
        int t  = k - f2 * T_;
        int dy = DY[t], dx = DX[t];
        bool v = ((unsigned)(py + dy) < H_) && ((unsigned)(px + dx) < W_);
        int q  = p + dy * W_ + dx;
        q = min(max(q, 0), P_ - 1);
        qs[kk] = q; f2s[kk] = f2;
        msk[kk] = v ? 1.f : 0.f;
    }
    float acc[8][4];
#pragma unroll
    for (int a = 0; a < 8; ++a)
#pragma unroll
        for (int b = 0; b < 4; ++b) acc[a][b] = 0.f;
#pragma unroll 1
    for (int ib = 0; ib < 8; ++ib) {
        h16x8 ph8[8];
#pragma unroll
        for (int f1 = 0; f1 < 8; ++f1)
            ph8[f1] = *(const h16x8*)(PH + (((size_t)f1 * 8 + ib) * P_ + p) * 8);
#pragma unroll
        for (int kk = 0; kk < 4; ++kk) {
            h16x8 th8 = *(const h16x8*)(TH + (((size_t)f2s[kk] * 8 + ib) * P_ + qs[kk]) * 8);
            h16x2 t0 = slice2(th8, 0), t1 = slice2(th8, 1),
                  t2 = slice2(th8, 2), t3 = slice2(th8, 3);
#pragma unroll
            for (int f1 = 0; f1 < 8; ++f1) {
                acc[f1][kk] = dot2(slice2(ph8[f1], 0), t0, acc[f1][kk]);
                acc[f1][kk] = dot2(slice2(ph8[f1], 1), t1, acc[f1][kk]);
                acc[f1][kk] = dot2(slice2(ph8[f1], 2), t2, acc[f1][kk]);
                acc[f1][kk] = dot2(slice2(ph8[f1], 3), t3, acc[f1][kk]);
            }
        }
    }
    // exp folded (|score| << 88); OOB -> exp(0)=1, matches reference denominator
#pragma unroll
    for (int kk = 0; kk < 4; ++kk) {
        u16x8 r;
#pragma unroll
        for (int f1 = 0; f1 < 8; ++f1) r[f1] = f2b(__expf(acc[f1][kk] * msk[kk]));
        *(u16x8*)(S + ((size_t)(k0 + kk) * P_ + p) * 8) = r;
    }
}

// MERGED attention apply: z<4 -> k_y quarter (Yp partial + den); z==4 -> k_yr.
// den accumulated ONLY when ib==0 (uniform branch) — other blocks skip the work.
__global__ __launch_bounds__(256) void k_attn(const u16* __restrict__ S,
                                              const u16* __restrict__ G,
                                              const float* __restrict__ SR,
                                              const float* __restrict__ Bf,
                                              const float* __restrict__ GR,
                                              u16* __restrict__ Yp,
                                              float* __restrict__ DEN,
                                              u16* __restrict__ Yr) {
    int p  = blockIdx.x * 256 + threadIdx.x;
    int ib = blockIdx.y;           // i-block: i = ib*8 + ii
    int z  = blockIdx.z;
    int px = p % W_, py = p / W_;
    if (z < 4) {
        int qtr = z;
        bool doDen = (ib == 0);    // block-uniform
        f32x2 acc2[8][4];
        float den[8];
#pragma unroll
        for (int a = 0; a < 8; ++a) {
            den[a] = 0.f;
#pragma unroll
            for (int b = 0; b < 4; ++b) acc2[a][b] = 0.f;
        }
#pragma unroll 1
        for (int f2 = qtr * 2; f2 < qtr * 2 + 2; ++f2) {
            const u16* Gb = G + (((size_t)f2 * 8 + ib) * P_) * 8;
#pragma unroll 1
            for (int t = 0; t < T_; ++t) {
                int dy = CDY[t], dx = CDX[t], k = CK[t];
                bool v = ((unsigned)(py + dy) < H_) && ((unsigned)(px + dx) < W_);
                int q  = p + dy * W_ + dx;
                q = min(max(q, 0), P_ - 1);
                float mt = v ? 1.f : 0.f;
                f32x2 mt2; mt2[0] = mt; mt2[1] = mt;
                u16x8 svv = *(const u16x8*)(S + ((size_t)(f2 * T_ + k) * P_ + p) * 8);
                float sv[8];
#pragma unroll
                for (int ff = 0; ff < 8; ++ff) sv[ff] = b2f(svv[ff]);
                h16x8 gh = *(const h16x8*)(Gb + (size_t)q * 8);
                f32x2 gv2[4];
#pragma unroll
                for (int jj = 0; jj < 4; ++jj) {
                    f32x2 g; g[0] = (float)gh[2*jj]; g[1] = (float)gh[2*jj+1];
                    gv2[jj] = g * mt2;           // v_pk_mul_f32
                }
                if (doDen) {
#pragma unroll
                    for (int ff = 0; ff < 8; ++ff) den[ff] += sv[ff];
                }
#pragma unroll
                for (int ff = 0; ff < 8; ++ff) {
                    f32x2 s2; s2[0] = sv[ff]; s2[1] = sv[ff];
#pragma unroll
                    for (int jj = 0; jj < 4; ++jj)
                        acc2[ff][jj] += s2 * gv2[jj];   // v_pk_fma_f32
                }
            }
        }
        if (doDen) {
#pragma unroll
            for (int ff = 0; ff < 8; ++ff)
                DEN[(size_t)(qtr * F_ + ff) * P_ + p] = den[ff];
        }
        u16* Yh = Yp + (size_t)qtr * F_ * P_ * I_;
#pragma unroll
        for (int ff = 0; ff < 8; ++ff) {
            u16x8 r;
#pragma unroll
            for (int ii = 0; ii < 8; ++ii) r[ii] = f2b(acc2[ff][ii >> 1][ii & 1]);
            *(u16x8*)(Yh + (((size_t)ff * 8 + ib) * P_ + p) * 8) = r;
        }
        return;
    }
    // z == 4: Yr path
    int i0 = ib * 8;
    float bfv[8];
#pragma unroll
    for (int f = 0; f < 8; ++f) bfv[f] = Bf[f * P_ + p];
    f32x2 acc2[8][4];
#pragma unroll
    for (int a = 0; a < 8; ++a)
#pragma unroll
        for (int b = 0; b < 4; ++b) acc2[a][b] = 0.f;
#pragma unroll
    for (int t = 0; t < T_; ++t) {
        int dy = DY[t], dx = DX[t];
        bool v = ((unsigned)(py + dy) < H_) && ((unsigned)(px + dx) < W_);
        int q  = p + dy * W_ + dx;
        q = min(max(q, 0), P_ - 1);
        float sr = SR[q];
        f32x2 gr2[4];
#pragma unroll
        for (int jj = 0; jj < 4; ++jj) {
            f32x2 g;
            g[0] = GR[(size_t)(i0 + 2*jj)     * P_ + q];
            g[1] = GR[(size_t)(i0 + 2*jj + 1) * P_ + q];
            gr2[jj] = g;
        }
#pragma unroll
        for (int f = 0; f < 8; ++f) {
            float fv = v ? fmaxf(sr + bfv[f], 0.f) * (1.f / (float)T_) : 0.f;
            f32x2 f2v; f2v[0] = fv; f2v[1] = fv;
#pragma unroll
            for (int jj = 0; jj < 4; ++jj) acc2[f][jj] += f2v * gr2[jj];
        }
    }
#pragma unroll
    for (int f = 0; f < 8; ++f) {
        u16x8 r;
#pragma unroll
        for (int ii = 0; ii < 8; ++ii) r[ii] = f2b(acc2[f][ii >> 1][ii & 1]);
        *(u16x8*)(Yr + (((size_t)f * 8 + ib) * P_ + p) * 8) = r;
    }
}

// MFMA final conv with fused fold: B-fragment for k<64 = bf16((sum_q Ypq)*dv);
// k>=64 = Yr. out[c][p] = MFMA + ball2[c] + x.
__global__ __launch_bounds__(256) void k_finalm(const u16* __restrict__ Yp,
                                                const u16* __restrict__ Yr,
                                                const float* __restrict__ DEN,
                                                const s16x8* __restrict__ Wpk2,
                                                const float* __restrict__ ball2,
                                                const float* __restrict__ x,
                                                float* __restrict__ out) {
    int wid  = threadIdx.x >> 6;
    int lane = threadIdx.x & 63;
    int px0  = blockIdx.x * 64 + wid * 16;
    int f    = blockIdx.y;
    int lm   = lane & 15;
    int lg   = lane >> 4;
    int p    = px0 + lm;
    float dv = 1.f / (DEN[(size_t)f * P_ + p]
                    + DEN[(size_t)(F_ + f) * P_ + p]
                    + DEN[(size_t)(2 * F_ + f) * P_ + p]
                    + DEN[(size_t)(3 * F_ + f) * P_ + p]);
    const size_t FPI = (size_t)F_ * P_ * I_;
    s16x8 bfrag[4];
#pragma unroll
    for (int ks = 0; ks < 4; ++ks) {
        int ip = ks * 32 + lg * 8;             // i' base of this lane's 8 k-elems
        if (ip < 64) {
            int ib = ip >> 3;
            size_t base = (((size_t)f * 8 + ib) * P_ + p) * 8;
            u16x8 q0 = *(const u16x8*)(Yp + base);
            u16x8 q1 = *(const u16x8*)(Yp + FPI + base);
            u16x8 q2 = *(const u16x8*)(Yp + 2 * FPI + base);
            u16x8 q3 = *(const u16x8*)(Yp + 3 * FPI + base);
            s16x8 r;
#pragma unroll
            for (int j = 0; j < 8; ++j)
                r[j] = (short)f2b((b2f(q0[j]) + b2f(q1[j]) + b2f(q2[j]) + b2f(q3[j])) * dv);
            bfrag[ks] = r;
        } else {
            int ib = (ip - 64) >> 3;
            bfrag[ks] = *(const s16x8*)(Yr + (((size_t)f * 8 + ib) * P_ + p) * 8);
        }
    }
#pragma unroll 1
    for (int nt = 0; nt < 8; ++nt) {
        f32x4 acc = {0.f, 0.f, 0.f, 0.f};
#pragma unroll
        for (int ks = 0; ks < 4; ++ks) {
            s16x8 afrag = Wpk2[(nt * 4 + ks) * 64 + lane];
            acc = __builtin_amdgcn_mfma_f32_16x16x32_bf16(afrag, bfrag[ks], acc, 0, 0, 0);
        }
        int nb = nt * 16 + lg * 4;             // 4 consecutive c in regs 0..3
#pragma unroll
        for (int r = 0; r < 4; ++r) {
            int c = nb + r;
            size_t o = ((size_t)f * C_ + c) * P_ + p;
            out[o] = acc[r] + ball2[c] + x[o];
        }
    }
}

extern "C" void kernel_launch(void* const* d_in, const int* in_sizes, int n_in,
                              void* d_out, int out_size, void* d_ws, size_t ws_size,
                              hipStream_t stream) {
    const float* x    = (const float*)d_in[0];
    const float* rgb  = (const float*)d_in[1];
    const float* g_w  = (const float*)d_in[2];
    const float* g_b  = (const float*)d_in[3];
    const float* th_w = (const float*)d_in[4];
    const float* th_b = (const float*)d_in[5];
    const float* ph_w = (const float*)d_in[6];
    const float* ph_b = (const float*)d_in[7];
    const float* W_w  = (const float*)d_in[8];
    const float* W_b  = (const float*)d_in[9];
    const float* rg_w = (const float*)d_in[10];
    const float* rg_b = (const float*)d_in[11];
    const float* rt_w = (const float*)d_in[12];
    const float* rt_b = (const float*)d_in[13];
    const float* rp_w = (const float*)d_in[14];
    const float* rp_b = (const float*)d_in[15];
    const float* rW_w = (const float*)d_in[16];
    const float* rW_b = (const float*)d_in[17];
    const float* cp_w = (const float*)d_in[18];
    float* out = (float*)d_out;

    const size_t FIP = (size_t)F_ * I_ * P_;   // 4718592
    const size_t SKP = (size_t)F_ * KK_ * P_;  // 10027008

    u16* Gb  = (u16*)d_ws;            // fp16 interleaved [f][ib][p][8]
    u16* THb = Gb  + FIP;             // fp16 interleaved
    u16* PHb = THb + FIP;             // fp16 interleaved
    u16* Sb  = PHb + FIP;             // bf16 [k][p][f1]
    u16* Yp  = Sb  + SKP;             // bf16 [4][f][ib][p][8]
    u16* Yr  = Yp  + 4 * FIP;         // bf16 [f][ib][p][8]
    float* GR  = (float*)(Yr + FIP);  // [i][p] fp32
    float* SR  = GR + (size_t)I_ * P_;
    float* Bf  = SR + P_;
    float* DEN = Bf + (size_t)F_ * P_;        // [4][f][p]
    float* VT  = DEN + 4 * (size_t)F_ * P_;
    float* U   = VT + C_;
    float* CT  = U + C_;
    unsigned* UH   = (unsigned*)(CT + 16);
    float* rgT = (float*)(UH + C2_);
    float* BALL = rgT + (size_t)C_ * I_;       // 256 floats
    _Float16* WPK = (_Float16*)(BALL + 256);   // 26624 halfs
    u16* WPK2   = (u16*)(WPK + 26624);         // 16384 bf16
    float* BALL2 = (float*)(WPK2 + 16384);     // 128 floats
    _Float16* XHT = (_Float16*)Yp;    // alias: xhT dead before k_attn writes Yp

    // scalar prep (produces U/CT needed by k_wprep)
    k_prep<<<1, 128, 0, stream>>>(rt_w, rp_w, rt_b, rp_b, cp_w, VT, U, CT, UH);

    // merged weight prep: Wpk/ball + Wpk2/ball2 + rgT
    k_wprep<<<200, 256, 0, stream>>>(g_w, th_w, ph_w, g_b, th_b, ph_b, U, CT,
                                     W_w, rW_w, W_b, rW_b, rg_w,
                                     WPK, BALL, WPK2, BALL2, rgT);

    // merged: x -> fp16 xhT (y<32) + rgb-side GR/SR (y>=32)
    k_xr<<<dim3(P_ / 256, 37), 256, 0, stream>>>(x, rgb, rgT, rg_b, VT, CT,
                                                 XHT, GR, SR);

    // MFMA projections -> interleaved fp16 (G, TH, PH) + Bf (n=192 row)
    k_projm<<<dim3(P_ / 64, 1, F_), 256, 0, stream>>>(XHT, (const h16x8*)WPK, BALL,
                                                      Gb, THb, PHb, Bf);

    // attention scores (interleaved PH/TH: 16B loads)
    k_scores<<<dim3(P_ / 256, KK_ / 4), 256, 0, stream>>>(PHb, THb, Sb);

    // merged attention apply: z<4 -> Yp quarters + den (den only at ib==0); z==4 -> Yr
    k_attn<<<dim3(P_ / 256, I_ / 8, 5), 256, 0, stream>>>(Sb, Gb, SR, Bf, GR,
                                                          Yp, DEN, Yr);

    // MFMA final with fused quarter-fold: K=128 concat(fold(Yp),Yr) x Wcat + bias + residual
    k_finalm<<<dim3(P_ / 64, F_), 256, 0, stream>>>(Yp, Yr, DEN, (const s16x8*)WPK2,
                                                    BALL2, x, out);
}